// Round 6
// baseline (102.811 us; speedup 1.0000x reference)
//
#include <hip/hip_runtime.h>
#include <hip/hip_bf16.h>

#define BDIM 256
#define NDIM 512
#define CDIM 1000
#define RDIM 64
#define BK 64
#define NT (NDIM / BK)   // 8 K-tiles

typedef __attribute__((ext_vector_type(4))) float f32x4;
typedef __attribute__((ext_vector_type(8))) short bf16x8;
typedef __attribute__((ext_vector_type(4))) unsigned int u32x4;

__device__ __forceinline__ uint32_t pk2(float lo, float hi) {
    unsigned short l = __builtin_bit_cast(unsigned short, __float2bfloat16(lo));
    unsigned short h = __builtin_bit_cast(unsigned short, __float2bfloat16(hi));
    return ((uint32_t)h << 16) | (uint32_t)l;
}

// ---------------------------------------------------------------------------
// Pre-pass: x fp32 [256][512] -> PLAIN row-major bf16 image in d_ws (256 KB).
// ---------------------------------------------------------------------------
__global__ __launch_bounds__(256)
void Mahalanobis_xconv_kernel(const float* __restrict__ x, u32x4* __restrict__ xbf)
{
    const int tid = blockIdx.x * 256 + threadIdx.x;   // 0..16383, 8 floats each
    const f32x4* src = reinterpret_cast<const f32x4*>(x) + (size_t)tid * 2;
    const f32x4 a = src[0], b = src[1];
    u32x4 pk = {pk2(a[0], a[1]), pk2(a[2], a[3]), pk2(b[0], b[1]), pk2(b[2], b[3])};
    xbf[tid] = pk;
}

// ---------------------------------------------------------------------------
// Main kernel: BARRIER-FREE. No LDS. One class per block, grid = 1000.
// 4 waves x 64 b-rows. Per (t,ks): A-frags from bf16 x image (L2-resident,
// 16B/lane contiguous), W-frags direct from fp32 global (32B/lane contiguous,
// HBM stream), in-register fp32->bf16 convert, MFMA. Sb (W·bias) accumulated
// redundantly per-wave in fp32, reduced with shfl_xor(16/32) — no shared state
// anywhere, so waves free-run and the compiler pipelines the unrolled K-loop.
// ---------------------------------------------------------------------------
__global__ __launch_bounds__(256, 2)
void Mahalanobis_72834055405642_kernel(const char* __restrict__ xbf,
                                       const float* __restrict__ w,
                                       const float* __restrict__ bias,
                                       float* __restrict__ out)
{
    const int tid  = threadIdx.x;
    const int lane = tid & 63;
    const int wv   = tid >> 6;
    const int l15  = lane & 15;
    const int lhi  = lane >> 4;
    const int c0   = blockIdx.x;

    // A: row = wv*64 + m*16 + l15, k = t*64 + ks*32 + lhi*8 (8 consecutive bf16)
    const char* xb = xbf + (size_t)(wv * 64 + l15) * (NDIM * 2) + lhi * 16;
    // B: row r = n*16 + l15, same k (8 consecutive fp32)
    const float* wb = w + (size_t)c0 * (RDIM * NDIM) + (size_t)l15 * NDIM + lhi * 8;
    const float* bb = bias + (size_t)c0 * NDIM + lhi * 8;

    f32x4 acc[4][4];
    #pragma unroll
    for (int m = 0; m < 4; ++m)
        #pragma unroll
        for (int n = 0; n < 4; ++n)
            acc[m][n] = (f32x4){0.f, 0.f, 0.f, 0.f};

    float sbp[4] = {0.f, 0.f, 0.f, 0.f};

    #pragma unroll
    for (int t = 0; t < NT; ++t) {
        #pragma unroll
        for (int ks = 0; ks < 2; ++ks) {
            const int ko = t * BK + ks * 32;          // k element offset

            // A-frags (bf16, 16 B contiguous per lane)
            bf16x8 af[4];
            #pragma unroll
            for (int m = 0; m < 4; ++m)
                af[m] = *reinterpret_cast<const bf16x8*>(
                    xb + (size_t)m * 16 * (NDIM * 2) + ko * 2);

            // W-frags (fp32, 32 B contiguous per lane)
            f32x4 wlo[4], whi[4];
            #pragma unroll
            for (int n = 0; n < 4; ++n) {
                const f32x4* wp = reinterpret_cast<const f32x4*>(
                    wb + (size_t)n * 16 * NDIM + ko);
                wlo[n] = wp[0];
                whi[n] = wp[1];
            }

            // bias frag (same k for all n-frags)
            const f32x4* bp = reinterpret_cast<const f32x4*>(bb + ko);
            const f32x4 blo = bp[0], bhi = bp[1];

            // fused fp32 Sb partial + fp32->bf16 convert
            bf16x8 bw[4];
            #pragma unroll
            for (int n = 0; n < 4; ++n) {
                sbp[n] += wlo[n][0]*blo[0] + wlo[n][1]*blo[1]
                        + wlo[n][2]*blo[2] + wlo[n][3]*blo[3]
                        + whi[n][0]*bhi[0] + whi[n][1]*bhi[1]
                        + whi[n][2]*bhi[2] + whi[n][3]*bhi[3];
                u32x4 pk = {pk2(wlo[n][0], wlo[n][1]), pk2(wlo[n][2], wlo[n][3]),
                            pk2(whi[n][0], whi[n][1]), pk2(whi[n][2], whi[n][3])};
                bw[n] = __builtin_bit_cast(bf16x8, pk);
            }

            #pragma unroll
            for (int m = 0; m < 4; ++m)
                #pragma unroll
                for (int n = 0; n < 4; ++n)
                    acc[m][n] = __builtin_amdgcn_mfma_f32_16x16x32_bf16(
                        af[m], bw[n], acc[m][n], 0, 0, 0);
        }
    }

    // Sb: sum the 4 lhi k-chunks; lane (l15) then holds Sb[r = n*16 + l15]
    #pragma unroll
    for (int n = 0; n < 4; ++n) {
        sbp[n] += __shfl_xor(sbp[n], 16);
        sbp[n] += __shfl_xor(sbp[n], 32);
    }

    // epilogue: out[b,c0] = sum_r (S - Sb)^2 ; butterfly over 16 lanes (r)
    #pragma unroll
    for (int m = 0; m < 4; ++m) {
        #pragma unroll
        for (int rg = 0; rg < 4; ++rg) {
            float p = 0.f;
            #pragma unroll
            for (int n = 0; n < 4; ++n) {
                const float d = acc[m][n][rg] - sbp[n];
                p += d * d;
            }
            #pragma unroll
            for (int s = 1; s < 16; s <<= 1)
                p += __shfl_xor(p, s);
            if (l15 == 0) {
                const int b = wv * 64 + m * 16 + lhi * 4 + rg;
                out[(size_t)b * CDIM + c0] = p;
            }
        }
    }
}

// ---------------------------------------------------------------------------
// Fallback (round-3 proven kernel) for ws_size < 256 KB
// ---------------------------------------------------------------------------
__global__ __launch_bounds__(256, 4)
void Mahalanobis_fallback_kernel(const float* __restrict__ x,
                                 const float* __restrict__ w,
                                 const float* __restrict__ bias,
                                 float* __restrict__ out)
{
    __shared__ alignas(16) char lds_x[BDIM * BK * 2];
    __shared__ alignas(16) char lds_w[RDIM * BK * 2];
    __shared__ float sb_lds[RDIM];

    const int tid  = threadIdx.x;
    const int lane = tid & 63;
    const int wv   = tid >> 6;
    const int l15  = lane & 15;
    const int lhi  = lane >> 4;
    const int c0   = blockIdx.x;

    const int jrow = tid >> 2;
    const int jq   = tid & 3;
    const float* wbase = w + (size_t)c0 * (RDIM * NDIM) + (size_t)jrow * NDIM + jq * 16;
    const float* bbase = bias + (size_t)c0 * NDIM + jq * 16;

    f32x4 acc[4][4];
    #pragma unroll
    for (int m = 0; m < 4; ++m)
        #pragma unroll
        for (int n = 0; n < 4; ++n)
            acc[m][n] = (f32x4){0.f, 0.f, 0.f, 0.f};

    float sbp = 0.f;
    const int swr = (l15 & 7) << 4;
    const int sww = (jrow & 7) << 4;
    const int xrow = tid >> 2;
    const int xq   = tid & 3;

    for (int t = 0; t < NT; ++t) {
        const float4* wsrc = reinterpret_cast<const float4*>(wbase + t * BK);
        const float4* bsrc = reinterpret_cast<const float4*>(bbase + t * BK);
        float4 w0 = wsrc[0], w1 = wsrc[1], w2 = wsrc[2], w3 = wsrc[3];
        float4 b0 = bsrc[0], b1 = bsrc[1], b2 = bsrc[2], b3 = bsrc[3];

        #pragma unroll
        for (int p = 0; p < 4; ++p) {
            const int r = p * 64 + xrow;
            const float4* s = reinterpret_cast<const float4*>(
                x + (size_t)r * NDIM + t * BK + xq * 16);
            float4 va = s[0], vb = s[1], vc = s[2], vd = s[3];
            uint4 pa = {pk2(va.x, va.y), pk2(va.z, va.w), pk2(vb.x, vb.y), pk2(vb.z, vb.w)};
            uint4 pb = {pk2(vc.x, vc.y), pk2(vc.z, vc.w), pk2(vd.x, vd.y), pk2(vd.z, vd.w)};
            const int sw = (r & 7) << 4;
            char* rowp = lds_x + r * 128;
            *reinterpret_cast<uint4*>(rowp + ((xq * 32) ^ sw))      = pa;
            *reinterpret_cast<uint4*>(rowp + ((xq * 32 + 16) ^ sw)) = pb;
        }

        sbp += w0.x*b0.x + w0.y*b0.y + w0.z*b0.z + w0.w*b0.w
             + w1.x*b1.x + w1.y*b1.y + w1.z*b1.z + w1.w*b1.w
             + w2.x*b2.x + w2.y*b2.y + w2.z*b2.z + w2.w*b2.w
             + w3.x*b3.x + w3.y*b3.y + w3.z*b3.z + w3.w*b3.w;
        {
            char* rowp = lds_w + jrow * 128;
            uint4 pa = {pk2(w0.x, w0.y), pk2(w0.z, w0.w), pk2(w1.x, w1.y), pk2(w1.z, w1.w)};
            uint4 pb = {pk2(w2.x, w2.y), pk2(w2.z, w2.w), pk2(w3.x, w3.y), pk2(w3.z, w3.w)};
            *reinterpret_cast<uint4*>(rowp + ((jq * 32) ^ sww))      = pa;
            *reinterpret_cast<uint4*>(rowp + ((jq * 32 + 16) ^ sww)) = pb;
        }

        __syncthreads();

        #pragma unroll
        for (int ks = 0; ks < 2; ++ks) {
            bf16x8 af[4];
            bf16x8 bfr[4];
            #pragma unroll
            for (int m = 0; m < 4; ++m) {
                const int row = wv * 64 + m * 16 + l15;
                af[m] = *reinterpret_cast<const bf16x8*>(
                    lds_x + row * 128 + ((ks * 64 + lhi * 16) ^ swr));
            }
            #pragma unroll
            for (int n = 0; n < 4; ++n) {
                const int row = n * 16 + l15;
                bfr[n] = *reinterpret_cast<const bf16x8*>(
                    lds_w + row * 128 + ((ks * 64 + lhi * 16) ^ swr));
            }
            #pragma unroll
            for (int m = 0; m < 4; ++m)
                #pragma unroll
                for (int n = 0; n < 4; ++n)
                    acc[m][n] = __builtin_amdgcn_mfma_f32_16x16x32_bf16(
                        af[m], bfr[n], acc[m][n], 0, 0, 0);
        }

        __syncthreads();
    }

    sbp += __shfl_xor(sbp, 1);
    sbp += __shfl_xor(sbp, 2);
    if (jq == 0) sb_lds[jrow] = sbp;
    __syncthreads();

    float sb[4];
    #pragma unroll
    for (int n = 0; n < 4; ++n) sb[n] = sb_lds[n * 16 + l15];

    #pragma unroll
    for (int m = 0; m < 4; ++m) {
        #pragma unroll
        for (int rg = 0; rg < 4; ++rg) {
            float p = 0.f;
            #pragma unroll
            for (int n = 0; n < 4; ++n) {
                const float d = acc[m][n][rg] - sb[n];
                p += d * d;
            }
            #pragma unroll
            for (int s = 1; s < 16; s <<= 1)
                p += __shfl_xor(p, s);
            if (l15 == 0) {
                const int b = wv * 64 + m * 16 + lhi * 4 + rg;
                out[(size_t)b * CDIM + c0] = p;
            }
        }
    }
}

extern "C" void kernel_launch(void* const* d_in, const int* in_sizes, int n_in,
                              void* d_out, int out_size, void* d_ws, size_t ws_size,
                              hipStream_t stream) {
    const float* x    = (const float*)d_in[0];
    const float* w    = (const float*)d_in[1];
    const float* bias = (const float*)d_in[2];
    float* out = (float*)d_out;

    if (ws_size >= (size_t)(BDIM * NDIM * 2)) {   // 256 KB bf16 x image
        hipLaunchKernelGGL(Mahalanobis_xconv_kernel, dim3(64), dim3(256), 0, stream,
                           x, (u32x4*)d_ws);
        hipLaunchKernelGGL(Mahalanobis_72834055405642_kernel, dim3(CDIM), dim3(256),
                           0, stream, (const char*)d_ws, w, bias, out);
    } else {
        hipLaunchKernelGGL(Mahalanobis_fallback_kernel, dim3(CDIM), dim3(256),
                           0, stream, x, w, bias, out);
    }
}

// Round 7
// 48.035 us; speedup vs baseline: 2.1403x; 2.1403x over previous
//
#include <hip/hip_runtime.h>
#include <hip/hip_bf16.h>

#define BDIM 256
#define NDIM 512
#define CDIM 1000
#define RDIM 64
#define BK 64
#define NT (NDIM / BK)   // 8 K-tiles

typedef __attribute__((ext_vector_type(4))) float f32x4;
typedef __attribute__((ext_vector_type(8))) short bf16x8;
typedef __attribute__((ext_vector_type(4))) unsigned int u32x4;

__device__ __forceinline__ uint32_t pk2(float lo, float hi) {
    unsigned short l = __builtin_bit_cast(unsigned short, __float2bfloat16(lo));
    unsigned short h = __builtin_bit_cast(unsigned short, __float2bfloat16(hi));
    return ((uint32_t)h << 16) | (uint32_t)l;
}

__device__ __forceinline__ void gload16(const void* g, void* l) {
    __builtin_amdgcn_global_load_lds(
        (const __attribute__((address_space(1))) void*)g,
        (__attribute__((address_space(3))) void*)l, 16, 0, 0);
}

// ---------------------------------------------------------------------------
// Pre-pass (proven r2/r3): x fp32 [256][512] -> bf16 swizzled BK=64 tile
// images in d_ws. Tile t: byte P = row*128 + sIn, sIn = uIn ^ ((row&7)<<4).
// ---------------------------------------------------------------------------
__global__ __launch_bounds__(256)
void Mahalanobis_xconv_kernel(const float* __restrict__ x, uint4* __restrict__ xws)
{
    const int tid = blockIdx.x * 256 + threadIdx.x;   // 0..16383
    const int t   = tid >> 11;                        // tile 0..7
    const int rem = tid & 2047;
    const int row = rem >> 3;                         // 0..255
    const int sIn = (rem & 7) << 4;                   // swizzled inner byte
    const int uIn = sIn ^ ((row & 7) << 4);           // unswizzled inner byte
    const int col0 = t * BK + (uIn >> 1);
    const float4* src = reinterpret_cast<const float4*>(x + (size_t)row * NDIM + col0);
    const float4 a = src[0], b = src[1];
    uint4 pk = {pk2(a.x, a.y), pk2(a.z, a.w), pk2(b.x, b.y), pk2(b.z, b.w)};
    xws[tid] = pk;
}

// ---------------------------------------------------------------------------
// Main kernel: m97-style issue-early gload_lds pipeline, ONE __syncthreads
// per iter (its vmcnt(0) drain IS the prefetch completion point).
//   - W staged fp32 via gload_lds, double-buffered, pre-swizzled source
//     (inner ^ (row&7)<<5); converted to bf16 at B-frag read time.
//   - x bf16 image slices are wave-private: overwrite guarded by a
//     wave-local lgkmcnt(0) fence only.
//   - Sb = W·bias fused, read from the fp32 W LDS tile.
// ---------------------------------------------------------------------------
__global__ __launch_bounds__(256, 2)
void Mahalanobis_72834055405642_kernel(const char* __restrict__ xws,
                                       const float* __restrict__ w,
                                       const float* __restrict__ bias,
                                       float* __restrict__ out)
{
    __shared__ alignas(16) char  lds_x[BDIM * BK * 2];      // 32 KB, wave-sliced
    __shared__ alignas(16) char  lds_w[2][RDIM * BK * 4];   // 2 x 16 KB fp32
    __shared__ alignas(16) float bias_lds[NDIM];            // 2 KB
    __shared__ float sb_lds[RDIM];                          // 256 B

    const int tid  = threadIdx.x;
    const int lane = tid & 63;
    const int wv   = tid >> 6;
    const int l15  = lane & 15;
    const int lhi  = lane >> 4;
    const int c0   = blockIdx.x;

    const char* wclass = reinterpret_cast<const char*>(w) + (size_t)c0 * (RDIM * NDIM * 4);
    const int   winner = (lane & 15) * 16;   // inner byte within a W row (0..240)

    // x staging (proven r3 pattern: wave-uniform LDS base, lane*16 implicit)
    auto issueX = [&](int t) {
        #pragma unroll
        for (int q = 0; q < 8; ++q)
            gload16(xws + (size_t)t * 32768 + wv * 8192 + q * 1024 + (size_t)lane * 16,
                    lds_x + wv * 8192 + q * 1024);
    };
    // W staging: LDS linear, global source pre-swizzled (rule #21)
    auto issueW = [&](int t, int buf) {
        #pragma unroll
        for (int q = 0; q < 4; ++q) {
            const int row = wv * 16 + q * 4 + (lane >> 4);            // 0..63
            const int src = row * 2048 + t * 256 + (winner ^ ((row & 7) << 5));
            gload16(wclass + src, lds_w[buf] + wv * 4096 + q * 1024);
        }
    };

    const int jrow = tid >> 2;      // Sb: W row 0..63
    const int jq   = tid & 3;       // Sb: k-quarter (16 floats)
    const int swzj = (jrow & 7) << 5;
    const int swr  = (l15 & 7) << 4;   // x-tile read swizzle (bf16, r3 proven)

    f32x4 acc[4][4];
    #pragma unroll
    for (int m = 0; m < 4; ++m)
        #pragma unroll
        for (int n = 0; n < 4; ++n)
            acc[m][n] = (f32x4){0.f, 0.f, 0.f, 0.f};

    float sbp = 0.f;

    // ---- prologue: bias -> LDS, stage x(0), W(0)
    {
        const float2 bv = *reinterpret_cast<const float2*>(
            bias + (size_t)c0 * NDIM + tid * 2);
        *reinterpret_cast<float2*>(bias_lds + tid * 2) = bv;
    }
    issueX(0);
    issueW(0, 0);
    __syncthreads();   // drains prologue gloads + bias ds_writes

    // ---- main loop: 1-deep issue-early pipeline
    #pragma unroll
    for (int t = 0; t < NT; ++t) {
        const char* wcur = lds_w[t & 1];

        // issue W(t+1) first — the HBM long pole rides over this whole iter
        if (t < NT - 1) issueW(t + 1, (t + 1) & 1);

        // A-frags (x slice is wave-private)
        bf16x8 af[4][2];
        #pragma unroll
        for (int m = 0; m < 4; ++m) {
            const int row = wv * 64 + m * 16 + l15;
            #pragma unroll
            for (int ks = 0; ks < 2; ++ks)
                af[m][ks] = *reinterpret_cast<const bf16x8*>(
                    lds_x + row * 128 + ((ks * 64 + lhi * 16) ^ swr));
        }

        // Sb partial from fp32 W tile (16 floats) + bias LDS
        {
            const char*  wp = wcur + jrow * 256;
            const float* bl = bias_lds + t * 64 + jq * 16;
            #pragma unroll
            for (int i = 0; i < 4; ++i) {
                const f32x4 wv4 = *reinterpret_cast<const f32x4*>(
                    wp + ((jq * 64 + i * 16) ^ swzj));
                const f32x4 bv4 = *reinterpret_cast<const f32x4*>(bl + i * 4);
                sbp += wv4[0]*bv4[0] + wv4[1]*bv4[1] + wv4[2]*bv4[2] + wv4[3]*bv4[3];
            }
        }

        // wave-local fence: af + Sb LDS reads complete, then overwrite x slice
        if (t < NT - 1) {
            asm volatile("s_waitcnt lgkmcnt(0)" ::: "memory");
            __builtin_amdgcn_sched_barrier(0);
            issueX(t + 1);
        }

        // B-frags: fp32 LDS -> cvt bf16 -> MFMA (just-in-time, low reg pressure)
        #pragma unroll
        for (int ks = 0; ks < 2; ++ks) {
            #pragma unroll
            for (int n = 0; n < 4; ++n) {
                const int r = n * 16 + l15;
                const char* pp = wcur + r * 256 +
                                 ((ks * 128 + lhi * 32) ^ ((r & 7) << 5));
                const f32x4 wlo = *reinterpret_cast<const f32x4*>(pp);
                const f32x4 whi = *reinterpret_cast<const f32x4*>(pp + 16);
                u32x4 pk = {pk2(wlo[0], wlo[1]), pk2(wlo[2], wlo[3]),
                            pk2(whi[0], whi[1]), pk2(whi[2], whi[3])};
                const bf16x8 bw = __builtin_bit_cast(bf16x8, pk);
                #pragma unroll
                for (int m = 0; m < 4; ++m)
                    acc[m][n] = __builtin_amdgcn_mfma_f32_16x16x32_bf16(
                        af[m][ks], bw, acc[m][n], 0, 0, 0);
            }
        }

        __syncthreads();   // drains t+1 gloads (vmcnt0) + orders buffer reuse
    }

    // ---- Sb: reduce 4 k-quarters (jq = lane&3), publish
    sbp += __shfl_xor(sbp, 1);
    sbp += __shfl_xor(sbp, 2);
    if (jq == 0) sb_lds[jrow] = sbp;
    __syncthreads();

    float sb[4];
    #pragma unroll
    for (int n = 0; n < 4; ++n) sb[n] = sb_lds[n * 16 + l15];

    // ---- epilogue: out[b,c0] = sum_r (S - Sb)^2
    #pragma unroll
    for (int m = 0; m < 4; ++m) {
        #pragma unroll
        for (int rg = 0; rg < 4; ++rg) {
            float p = 0.f;
            #pragma unroll
            for (int n = 0; n < 4; ++n) {
                const float d = acc[m][n][rg] - sb[n];
                p += d * d;
            }
            #pragma unroll
            for (int s = 1; s < 16; s <<= 1)
                p += __shfl_xor(p, s);
            if (l15 == 0) {
                const int b = wv * 64 + m * 16 + lhi * 4 + rg;
                out[(size_t)b * CDIM + c0] = p;
            }
        }
    }
}

// ---------------------------------------------------------------------------
// Fallback (round-3 proven kernel) for ws_size < 256 KB
// ---------------------------------------------------------------------------
__global__ __launch_bounds__(256, 4)
void Mahalanobis_fallback_kernel(const float* __restrict__ x,
                                 const float* __restrict__ w,
                                 const float* __restrict__ bias,
                                 float* __restrict__ out)
{
    __shared__ alignas(16) char lds_x[BDIM * BK * 2];
    __shared__ alignas(16) char lds_w[RDIM * BK * 2];
    __shared__ float sb_lds[RDIM];

    const int tid  = threadIdx.x;
    const int lane = tid & 63;
    const int wv   = tid >> 6;
    const int l15  = lane & 15;
    const int lhi  = lane >> 4;
    const int c0   = blockIdx.x;

    const int jrow = tid >> 2;
    const int jq   = tid & 3;
    const float* wbase = w + (size_t)c0 * (RDIM * NDIM) + (size_t)jrow * NDIM + jq * 16;
    const float* bbase = bias + (size_t)c0 * NDIM + jq * 16;

    f32x4 acc[4][4];
    #pragma unroll
    for (int m = 0; m < 4; ++m)
        #pragma unroll
        for (int n = 0; n < 4; ++n)
            acc[m][n] = (f32x4){0.f, 0.f, 0.f, 0.f};

    float sbp = 0.f;
    const int swr = (l15 & 7) << 4;
    const int sww = (jrow & 7) << 4;
    const int xrow = tid >> 2;
    const int xq   = tid & 3;

    for (int t = 0; t < NT; ++t) {
        const float4* wsrc = reinterpret_cast<const float4*>(wbase + t * BK);
        const float4* bsrc = reinterpret_cast<const float4*>(bbase + t * BK);
        float4 w0 = wsrc[0], w1 = wsrc[1], w2 = wsrc[2], w3 = wsrc[3];
        float4 b0 = bsrc[0], b1 = bsrc[1], b2 = bsrc[2], b3 = bsrc[3];

        #pragma unroll
        for (int p = 0; p < 4; ++p) {
            const int r = p * 64 + xrow;
            const float4* s = reinterpret_cast<const float4*>(
                x + (size_t)r * NDIM + t * BK + xq * 16);
            float4 va = s[0], vb = s[1], vc = s[2], vd = s[3];
            uint4 pa = {pk2(va.x, va.y), pk2(va.z, va.w), pk2(vb.x, vb.y), pk2(vb.z, vb.w)};
            uint4 pb = {pk2(vc.x, vc.y), pk2(vc.z, vc.w), pk2(vd.x, vd.y), pk2(vd.z, vd.w)};
            const int sw = (r & 7) << 4;
            char* rowp = lds_x + r * 128;
            *reinterpret_cast<uint4*>(rowp + ((xq * 32) ^ sw))      = pa;
            *reinterpret_cast<uint4*>(rowp + ((xq * 32 + 16) ^ sw)) = pb;
        }

        sbp += w0.x*b0.x + w0.y*b0.y + w0.z*b0.z + w0.w*b0.w
             + w1.x*b1.x + w1.y*b1.y + w1.z*b1.z + w1.w*b1.w
             + w2.x*b2.x + w2.y*b2.y + w2.z*b2.z + w2.w*b2.w
             + w3.x*b3.x + w3.y*b3.y + w3.z*b3.z + w3.w*b3.w;
        {
            char* rowp = lds_w + jrow * 128;
            uint4 pa = {pk2(w0.x, w0.y), pk2(w0.z, w0.w), pk2(w1.x, w1.y), pk2(w1.z, w1.w)};
            uint4 pb = {pk2(w2.x, w2.y), pk2(w2.z, w2.w), pk2(w3.x, w3.y), pk2(w3.z, w3.w)};
            *reinterpret_cast<uint4*>(rowp + ((jq * 32) ^ sww))      = pa;
            *reinterpret_cast<uint4*>(rowp + ((jq * 32 + 16) ^ sww)) = pb;
        }

        __syncthreads();

        #pragma unroll
        for (int ks = 0; ks < 2; ++ks) {
            bf16x8 af[4];
            bf16x8 bfr[4];
            #pragma unroll
            for (int m = 0; m < 4; ++m) {
                const int row = wv * 64 + m * 16 + l15;
                af[m] = *reinterpret_cast<const bf16x8*>(
                    lds_x + row * 128 + ((ks * 64 + lhi * 16) ^ swr));
            }
            #pragma unroll
            for (int n = 0; n < 4; ++n) {
                const int row = n * 16 + l15;
                bfr[n] = *reinterpret_cast<const bf16x8*>(
                    lds_w + row * 128 + ((ks * 64 + lhi * 16) ^ swr));
            }
            #pragma unroll
            for (int m = 0; m < 4; ++m)
                #pragma unroll
                for (int n = 0; n < 4; ++n)
                    acc[m][n] = __builtin_amdgcn_mfma_f32_16x16x32_bf16(
                        af[m], bfr[n], acc[m][n], 0, 0, 0);
        }

        __syncthreads();
    }

    sbp += __shfl_xor(sbp, 1);
    sbp += __shfl_xor(sbp, 2);
    if (jq == 0) sb_lds[jrow] = sbp;
    __syncthreads();

    float sb[4];
    #pragma unroll
    for (int n = 0; n < 4; ++n) sb[n] = sb_lds[n * 16 + l15];

    #pragma unroll
    for (int m = 0; m < 4; ++m) {
        #pragma unroll
        for (int rg = 0; rg < 4; ++rg) {
            float p = 0.f;
            #pragma unroll
            for (int n = 0; n < 4; ++n) {
                const float d = acc[m][n][rg] - sb[n];
                p += d * d;
            }
            #pragma unroll
            for (int s = 1; s < 16; s <<= 1)
                p += __shfl_xor(p, s);
            if (l15 == 0) {
                const int b = wv * 64 + m * 16 + lhi * 4 + rg;
                out[(size_t)b * CDIM + c0] = p;
            }
        }
    }
}

extern "C" void kernel_launch(void* const* d_in, const int* in_sizes, int n_in,
                              void* d_out, int out_size, void* d_ws, size_t ws_size,
                              hipStream_t stream) {
    const float* x    = (const float*)d_in[0];
    const float* w    = (const float*)d_in[1];
    const float* bias = (const float*)d_in[2];
    float* out = (float*)d_out;

    if (ws_size >= (size_t)(BDIM * NDIM * 2)) {   // 256 KB bf16 x tile images
        hipLaunchKernelGGL(Mahalanobis_xconv_kernel, dim3(64), dim3(256), 0, stream,
                           x, (uint4*)d_ws);
        hipLaunchKernelGGL(Mahalanobis_72834055405642_kernel, dim3(CDIM), dim3(256),
                           0, stream, (const char*)d_ws, w, bias, out);
    } else {
        hipLaunchKernelGGL(Mahalanobis_fallback_kernel, dim3(CDIM), dim3(256),
                           0, stream, x, w, bias, out);
    }
}